// Round 1
// baseline (1086.181 us; speedup 1.0000x reference)
//
#include <hip/hip_runtime.h>
#include <math.h>

// ---------------------------------------------------------------------------
// GATNet pipeline, MI355X round 0 (correctness-first f32 implementation)
// ---------------------------------------------------------------------------

static __device__ __forceinline__ float leaky02(float e){ return e >= 0.f ? e : 0.2f*e; }

// ---------- column sum-of-squares (for l2norm_dim0 folding) ----------
__global__ void colnorm_sq(const float* __restrict__ X, float* __restrict__ ss, int R, int C){
  int c = blockIdx.x*blockDim.x + threadIdx.x;
  if (c >= C) return;
  int r0 = blockIdx.y * 128;
  int r1 = r0 + 128; if (r1 > R) r1 = R;
  float s = 0.f;
  for (int r = r0; r < r1; ++r){ float v = X[(size_t)r*C + c]; s = fmaf(v, v, s); }
  atomicAdd(&ss[c], s);
}

// Wo[j,k] = W[j,k] / max(sqrt(ss[j]), 1e-12)
__global__ void scale_rows(const float* __restrict__ W, const float* __restrict__ ss,
                           float* __restrict__ Wo, int K, int C){
  int i = blockIdx.x*blockDim.x + threadIdx.x;
  if (i >= K*C) return;
  int row = i / C;
  float n = fmaxf(sqrtf(ss[row]), 1e-12f);
  Wo[i] = W[i] / n;
}

// ---------- generic f32 tiled GEMM: C[M,N] = A[M,K] @ B[K,N] ----------
// assumes M%64==0, N%64==0, K%16==0
__global__ __launch_bounds__(256) void gemm_f32(const float* __restrict__ A,
    const float* __restrict__ B, float* __restrict__ C, int M, int N, int K){
  __shared__ float As[16][65];
  __shared__ float Bs[16][65];
  int tid = threadIdx.x;
  int tx = tid & 15, ty = tid >> 4;
  int rowBase = blockIdx.y << 6, colBase = blockIdx.x << 6;
  float acc[4][4] = {{0.f}};
  for (int k0 = 0; k0 < K; k0 += 16){
    #pragma unroll
    for (int i = 0; i < 4; i++){
      int l = tid + i*256; int r = l >> 4, c = l & 15;
      As[c][r] = A[(size_t)(rowBase + r)*K + k0 + c];
    }
    #pragma unroll
    for (int i = 0; i < 4; i++){
      int l = tid + i*256; int r = l >> 6, c = l & 63;
      Bs[r][c] = B[(size_t)(k0 + r)*N + colBase + c];
    }
    __syncthreads();
    #pragma unroll
    for (int kk = 0; kk < 16; kk++){
      float a[4], b[4];
      #pragma unroll
      for (int i = 0; i < 4; i++){ a[i] = As[kk][ty*4+i]; b[i] = Bs[kk][tx*4+i]; }
      #pragma unroll
      for (int i = 0; i < 4; i++)
        #pragma unroll
        for (int j = 0; j < 4; j++) acc[i][j] = fmaf(a[i], b[j], acc[i][j]);
    }
    __syncthreads();
  }
  #pragma unroll
  for (int i = 0; i < 4; i++)
    #pragma unroll
    for (int j = 0; j < 4; j++)
      C[(size_t)(rowBase + ty*4 + i)*N + colBase + tx*4 + j] = acc[i][j];
}

// ---------- GAT attention coefficients ----------
__global__ __launch_bounds__(256) void att_kernel(const float* __restrict__ h,
    const float* __restrict__ att_src, const float* __restrict__ att_dst,
    float* __restrict__ asrc, float* __restrict__ adst, int N){
  __shared__ float4 red[256];
  int i = blockIdx.x, t = threadIdx.x;
  float h0 = h[(size_t)i*512 + t];
  float h1 = h[(size_t)i*512 + 256 + t];
  float4 v = make_float4(h0*att_src[t], h1*att_src[256+t], h0*att_dst[t], h1*att_dst[256+t]);
  red[t] = v; __syncthreads();
  for (int s = 128; s > 0; s >>= 1){
    if (t < s){ red[t].x += red[t+s].x; red[t].y += red[t+s].y;
                red[t].z += red[t+s].z; red[t].w += red[t+s].w; }
    __syncthreads();
  }
  if (t == 0){ asrc[2*i] = red[0].x; asrc[2*i+1] = red[0].y;
               adst[2*i] = red[0].z; adst[2*i+1] = red[0].w; }
}

// ---------- CSR build ----------
__global__ void deg_init(int* deg, int N){
  int i = blockIdx.x*blockDim.x + threadIdx.x;
  if (i < N) deg[i] = 1;   // self-loop
}
__global__ void deg_count(const int* __restrict__ dst, int* deg, int E){
  int e = blockIdx.x*blockDim.x + threadIdx.x;
  if (e < E) atomicAdd(&deg[dst[e]], 1);
}
// single-block exclusive scan (n <= 32768)
__global__ __launch_bounds__(1024) void scan_kernel(const int* __restrict__ deg,
                                                    int* __restrict__ offs, int n){
  __shared__ int part[1024];
  int t = threadIdx.x;
  int chunk = (n + 1023) >> 10;
  int base = t * chunk;
  int loc[32];
  int local = 0;
  for (int k = 0; k < chunk; k++){
    int idx = base + k; loc[k] = local;
    if (idx < n) local += deg[idx];
  }
  part[t] = local; __syncthreads();
  for (int off = 1; off < 1024; off <<= 1){
    int v = (t >= off) ? part[t-off] : 0; __syncthreads();
    part[t] += v; __syncthreads();
  }
  int excl = part[t] - local;
  for (int k = 0; k < chunk; k++){
    int idx = base + k;
    if (idx < n) offs[idx] = excl + loc[k];
  }
  if (t == 1023) offs[n] = part[1023];
}
__global__ void copy_int(const int* __restrict__ a, int* __restrict__ b, int n){
  int i = blockIdx.x*blockDim.x + threadIdx.x;
  if (i < n) b[i] = a[i];
}
__global__ void scatter_edges(const int* __restrict__ src, const int* __restrict__ dst,
                              int* cursor, int* __restrict__ ssrc, int E, int N){
  int e = blockIdx.x*blockDim.x + threadIdx.x;
  if (e < E){
    int d = dst[e]; int pos = atomicAdd(&cursor[d], 1); ssrc[pos] = src[e];
  } else if (e < E + N){
    int i = e - E; int pos = atomicAdd(&cursor[i], 1); ssrc[pos] = i;
  }
}

// ---------- GAT aggregation (one block per destination node) ----------
__global__ __launch_bounds__(256) void gat_aggregate(const float* __restrict__ h,
    const int* __restrict__ offs, const int* __restrict__ ssrc,
    const float* __restrict__ asrc, const float* __restrict__ adst,
    const float* __restrict__ bias, float* __restrict__ out, int N){
  __shared__ float2 red[256];
  int d = blockIdx.x, t = threadIdx.x;
  int beg = offs[d], end = offs[d+1];
  float ad0 = adst[2*d], ad1 = adst[2*d+1];
  // pass 1: per-head max
  float m0 = -1e30f, m1 = -1e30f;
  for (int o = beg + t; o < end; o += 256){
    int s = ssrc[o];
    m0 = fmaxf(m0, leaky02(asrc[2*s]   + ad0));
    m1 = fmaxf(m1, leaky02(asrc[2*s+1] + ad1));
  }
  red[t] = make_float2(m0, m1); __syncthreads();
  for (int s2 = 128; s2 > 0; s2 >>= 1){
    if (t < s2){ red[t].x = fmaxf(red[t].x, red[t+s2].x);
                 red[t].y = fmaxf(red[t].y, red[t+s2].y); }
    __syncthreads();
  }
  m0 = red[0].x; m1 = red[0].y; __syncthreads();
  // pass 2: denominators
  float s0 = 0.f, s1 = 0.f;
  for (int o = beg + t; o < end; o += 256){
    int s = ssrc[o];
    s0 += expf(leaky02(asrc[2*s]   + ad0) - m0);
    s1 += expf(leaky02(asrc[2*s+1] + ad1) - m1);
  }
  red[t] = make_float2(s0, s1); __syncthreads();
  for (int s2 = 128; s2 > 0; s2 >>= 1){
    if (t < s2){ red[t].x += red[t+s2].x; red[t].y += red[t+s2].y; }
    __syncthreads();
  }
  float inv0 = 1.f / red[0].x, inv1 = 1.f / red[0].y;
  __syncthreads();
  // pass 3: weighted accumulation; thread t owns dims (2t, 2t+1)
  int dim = 2*t;
  int head = dim >> 8;
  float mh   = head ? m1   : m0;
  float invh = head ? inv1 : inv0;
  float adh  = head ? ad1  : ad0;
  float accx = 0.f, accy = 0.f;
  for (int o = beg; o < end; ++o){
    int s = ssrc[o];
    float al = expf(leaky02(asrc[2*s + head] + adh) - mh) * invh;
    float2 v = *(const float2*)&h[(size_t)s*512 + dim];
    accx = fmaf(al, v.x, accx);
    accy = fmaf(al, v.y, accy);
  }
  out[(size_t)d*512 + dim]     = fmaxf(accx + bias[dim],   0.f);   // conv bias + relu
  out[(size_t)d*512 + dim + 1] = fmaxf(accy + bias[dim+1], 0.f);
}

// ---------- bias + LayerNorm + ReLU (in place), C <= 256 ----------
__global__ __launch_bounds__(256) void ln_relu(float* __restrict__ Z,
    const float* __restrict__ bias, const float* __restrict__ g,
    const float* __restrict__ bg, int R, int C){
  __shared__ float red[256];
  int r = blockIdx.x, t = threadIdx.x;
  bool act = t < C;
  float z = 0.f;
  if (act) z = Z[(size_t)r*C + t] + bias[t];
  red[t] = z; __syncthreads();
  for (int s = 128; s > 0; s >>= 1){ if (t < s) red[t] += red[t+s]; __syncthreads(); }
  float mean = red[0] / C; __syncthreads();
  float dz = act ? z - mean : 0.f;
  red[t] = dz*dz; __syncthreads();
  for (int s = 128; s > 0; s >>= 1){ if (t < s) red[t] += red[t+s]; __syncthreads(); }
  float var = red[0] / C;
  float rs = 1.f / sqrtf(var + 1e-5f);
  if (act) Z[(size_t)r*C + t] = fmaxf(dz*rs*g[t] + bg[t], 0.f);
}

// ---------- final 64->3 GEMM, packs (x,y,z,|h|^2) ----------
__global__ __launch_bounds__(256) void final_hf4(const float* __restrict__ A,
    const float* __restrict__ W3s, const float* __restrict__ b3,
    float4* __restrict__ hf4, int N){
  __shared__ float w[64*3];
  __shared__ float b[3];
  if (threadIdx.x < 192) w[threadIdx.x] = W3s[threadIdx.x];
  if (threadIdx.x < 3)   b[threadIdx.x] = b3[threadIdx.x];
  __syncthreads();
  int r = blockIdx.x*blockDim.x + threadIdx.x;
  if (r >= N) return;
  float x = b[0], y = b[1], z = b[2];
  #pragma unroll 8
  for (int k = 0; k < 64; ++k){
    float a = A[(size_t)r*64 + k];
    x = fmaf(a, w[k*3],   x);
    y = fmaf(a, w[k*3+1], y);
    z = fmaf(a, w[k*3+2], z);
  }
  float sq = x*x + y*y + z*z;
  hf4[r] = make_float4(x, y, z, sq);
}

// ---------- cdist: out[i,j] = sqrt(max(sq_i + sq_j - 2<h_i,h_j>, 0)) ----------
__global__ __launch_bounds__(256) void cdist_kernel(const float4* __restrict__ hf,
                                                    float* __restrict__ out, int N){
  int i = blockIdx.y;
  int j0 = (blockIdx.x*256 + threadIdx.x)*4;
  float4 a = hf[i];
  float4 r;
  float4 b0 = hf[j0], b1 = hf[j0+1], b2 = hf[j0+2], b3 = hf[j0+3];
  float d;
  d = a.w + b0.w - 2.f*(a.x*b0.x + a.y*b0.y + a.z*b0.z); r.x = sqrtf(fmaxf(d, 0.f));
  d = a.w + b1.w - 2.f*(a.x*b1.x + a.y*b1.y + a.z*b1.z); r.y = sqrtf(fmaxf(d, 0.f));
  d = a.w + b2.w - 2.f*(a.x*b2.x + a.y*b2.y + a.z*b2.z); r.z = sqrtf(fmaxf(d, 0.f));
  d = a.w + b3.w - 2.f*(a.x*b3.x + a.y*b3.y + a.z*b3.z); r.w = sqrtf(fmaxf(d, 0.f));
  *(float4*)&out[(size_t)i*N + j0] = r;
}

// ---------------------------------------------------------------------------
extern "C" void kernel_launch(void* const* d_in, const int* in_sizes, int n_in,
                              void* d_out, int out_size, void* d_ws, size_t ws_size,
                              hipStream_t stream){
  const int N = in_sizes[0] / 512;        // 16384
  const int E = in_sizes[1] / 2;          // 524288

  const float* x         = (const float*)d_in[0];
  const int*   ei        = (const int*)  d_in[1];
  const float* W         = (const float*)d_in[2];
  const float* att_src   = (const float*)d_in[3];
  const float* att_dst   = (const float*)d_in[4];
  const float* bias_conv = (const float*)d_in[5];
  const float* Wa  = (const float*)d_in[6];
  const float* ba  = (const float*)d_in[7];
  const float* ga  = (const float*)d_in[8];
  const float* bga = (const float*)d_in[9];
  const float* W1  = (const float*)d_in[10];
  const float* b1  = (const float*)d_in[11];
  const float* g1  = (const float*)d_in[12];
  const float* bg1 = (const float*)d_in[13];
  const float* W2  = (const float*)d_in[14];
  const float* b2  = (const float*)d_in[15];
  const float* g2  = (const float*)d_in[16];
  const float* bg2 = (const float*)d_in[17];
  const float* W3  = (const float*)d_in[18];
  const float* b3  = (const float*)d_in[19];

  const int* e_src = ei;
  const int* e_dst = ei + E;

  // workspace layout
  size_t off = 0;
  auto alloc = [&](size_t bytes)->char*{
    size_t o = off; off += (bytes + 255) & ~(size_t)255;
    return (char*)d_ws + o;
  };
  float* bufA  = (float*)alloc((size_t)N*512*4);
  float* bufB  = (float*)alloc((size_t)N*512*4);
  float* Wsc   = (float*)alloc(512*512*4);
  float* Wasc  = (float*)alloc(512*256*4);
  float* W1sc  = (float*)alloc(256*128*4);
  float* W2sc  = (float*)alloc(128*64*4);
  float* W3sc  = (float*)alloc(64*3*4);
  float* ss    = (float*)alloc(512*4);
  float* asrc  = (float*)alloc((size_t)N*2*4);
  float* adst  = (float*)alloc((size_t)N*2*4);
  float4* hf4  = (float4*)alloc((size_t)N*16);
  int* deg     = (int*)alloc((size_t)N*4);
  int* offs    = (int*)alloc((size_t)(N+1)*4);
  int* cursor  = (int*)alloc((size_t)N*4);
  int* ssrc    = (int*)alloc((size_t)(E+N)*4);

  float* outF = (float*)d_out;

  // ---- stage 1: l2norm(x) folded into W ; h = x @ W' ----
  hipMemsetAsync(ss, 0, 512*4, stream);
  colnorm_sq<<<dim3(2,128), 256, 0, stream>>>(x, ss, N, 512);
  scale_rows<<<(512*512+255)/256, 256, 0, stream>>>(W, ss, Wsc, 512, 512);
  gemm_f32<<<dim3(512/64, N/64), 256, 0, stream>>>(x, Wsc, bufA, N, 512, 512);

  // ---- GAT ----
  att_kernel<<<N, 256, 0, stream>>>(bufA, att_src, att_dst, asrc, adst, N);
  deg_init<<<(N+255)/256, 256, 0, stream>>>(deg, N);
  deg_count<<<(E+255)/256, 256, 0, stream>>>(e_dst, deg, E);
  scan_kernel<<<1, 1024, 0, stream>>>(deg, offs, N);
  copy_int<<<(N+255)/256, 256, 0, stream>>>(offs, cursor, N);
  scatter_edges<<<(E+N+255)/256, 256, 0, stream>>>(e_src, e_dst, cursor, ssrc, E, N);
  gat_aggregate<<<N, 256, 0, stream>>>(bufA, offs, ssrc, asrc, adst, bias_conv, bufB, N);

  // ---- stage 2: l2norm fold -> hA = LN(relu'd_gatout @ Wa' + ba) ----
  hipMemsetAsync(ss, 0, 512*4, stream);
  colnorm_sq<<<dim3(2,128), 256, 0, stream>>>(bufB, ss, N, 512);
  scale_rows<<<(512*256+255)/256, 256, 0, stream>>>(Wa, ss, Wasc, 512, 256);
  gemm_f32<<<dim3(256/64, N/64), 256, 0, stream>>>(bufB, Wasc, bufA, N, 256, 512);
  ln_relu<<<N, 256, 0, stream>>>(bufA, ba, ga, bga, N, 256);

  // ---- stage 3 ----
  hipMemsetAsync(ss, 0, 512*4, stream);
  colnorm_sq<<<dim3(1,128), 256, 0, stream>>>(bufA, ss, N, 256);
  scale_rows<<<(256*128+255)/256, 256, 0, stream>>>(W1, ss, W1sc, 256, 128);
  gemm_f32<<<dim3(128/64, N/64), 256, 0, stream>>>(bufA, W1sc, bufB, N, 128, 256);
  ln_relu<<<N, 256, 0, stream>>>(bufB, b1, g1, bg1, N, 128);

  // ---- stage 4 ----
  hipMemsetAsync(ss, 0, 512*4, stream);
  colnorm_sq<<<dim3(1,128), 256, 0, stream>>>(bufB, ss, N, 128);
  scale_rows<<<(128*64+255)/256, 256, 0, stream>>>(W2, ss, W2sc, 128, 64);
  gemm_f32<<<dim3(64/64, N/64), 256, 0, stream>>>(bufB, W2sc, bufA, N, 64, 128);
  ln_relu<<<N, 256, 0, stream>>>(bufA, b2, g2, bg2, N, 64);

  // ---- stage 5: final projection + cdist ----
  hipMemsetAsync(ss, 0, 512*4, stream);
  colnorm_sq<<<dim3(1,128), 256, 0, stream>>>(bufA, ss, N, 64);
  scale_rows<<<(64*3+255)/256, 256, 0, stream>>>(W3, ss, W3sc, 64, 3);
  final_hf4<<<(N+255)/256, 256, 0, stream>>>(bufA, W3sc, b3, hf4, N);
  cdist_kernel<<<dim3(N/1024, N), 256, 0, stream>>>(hf4, outF, N);
}

// Round 2
// 901.543 us; speedup vs baseline: 1.2048x; 1.2048x over previous
//
#include <hip/hip_runtime.h>
#include <math.h>

// ---------------------------------------------------------------------------
// GATNet pipeline, MI355X round 1: split-bf16 MFMA for the two big GEMMs,
// LDS-cached alphas in GAT aggregation.
// ---------------------------------------------------------------------------

typedef __bf16 bf16x8 __attribute__((ext_vector_type(8)));
typedef __bf16 bf16x4 __attribute__((ext_vector_type(4)));
typedef float  f32x4  __attribute__((ext_vector_type(4)));
typedef short  short8 __attribute__((ext_vector_type(8)));

static __device__ __forceinline__ float leaky02(float e){ return e >= 0.f ? e : 0.2f*e; }

// ---------- column sum-of-squares (for l2norm_dim0 folding) ----------
__global__ void colnorm_sq(const float* __restrict__ X, float* __restrict__ ss, int R, int C){
  int c = blockIdx.x*blockDim.x + threadIdx.x;
  if (c >= C) return;
  int r0 = blockIdx.y * 128;
  int r1 = r0 + 128; if (r1 > R) r1 = R;
  float s = 0.f;
  for (int r = r0; r < r1; ++r){ float v = X[(size_t)r*C + c]; s = fmaf(v, v, s); }
  atomicAdd(&ss[c], s);
}

// Wo[j,k] = W[j,k] / max(sqrt(ss[j]), 1e-12)
__global__ void scale_rows(const float* __restrict__ W, const float* __restrict__ ss,
                           float* __restrict__ Wo, int K, int C){
  int i = blockIdx.x*blockDim.x + threadIdx.x;
  if (i >= K*C) return;
  int row = i / C;
  float n = fmaxf(sqrtf(ss[row]), 1e-12f);
  Wo[i] = W[i] / n;
}

// ---------- split f32 -> bf16 hi + bf16 lo (elementwise, x4 vectorized) ----------
__global__ __launch_bounds__(256) void split_hl(const float* __restrict__ X,
    __bf16* __restrict__ H, __bf16* __restrict__ L, int n4){
  int i = blockIdx.x*256 + threadIdx.x;
  if (i >= n4) return;
  float4 v = ((const float4*)X)[i];
  bf16x4 hv, lv;
  hv[0] = (__bf16)v.x; lv[0] = (__bf16)(v.x - (float)hv[0]);
  hv[1] = (__bf16)v.y; lv[1] = (__bf16)(v.y - (float)hv[1]);
  hv[2] = (__bf16)v.z; lv[2] = (__bf16)(v.z - (float)hv[2]);
  hv[3] = (__bf16)v.w; lv[3] = (__bf16)(v.w - (float)hv[3]);
  ((bf16x4*)H)[i] = hv;
  ((bf16x4*)L)[i] = lv;
}

// ---------- split + transpose B[K][N] -> TH/TL [N][K] bf16 ----------
__global__ __launch_bounds__(256) void split_tr(const float* __restrict__ B,
    __bf16* __restrict__ TH, __bf16* __restrict__ TL, int K, int N){
  __shared__ float tile[32][33];
  int lx = threadIdx.x & 31, ly = threadIdx.x >> 5;   // ly: 0..7
  int kb = blockIdx.y*32, nb = blockIdx.x*32;
  #pragma unroll
  for (int i = 0; i < 4; i++)
    tile[ly + i*8][lx] = B[(size_t)(kb + ly + i*8)*N + nb + lx];
  __syncthreads();
  #pragma unroll
  for (int i = 0; i < 4; i++){
    int nl = ly + i*8;
    float v = tile[lx][nl];
    __bf16 h = (__bf16)v;
    TH[(size_t)(nb + nl)*K + kb + lx] = h;
    TL[(size_t)(nb + nl)*K + kb + lx] = (__bf16)(v - (float)h);
  }
}

// ---------- split-bf16 MFMA GEMM: C[M,N] = (Ah+Al)[M,K] @ (Bh+Bl)[K,N] ----------
// A given row-major hi/lo; B given TRANSPOSED row-major hi/lo ([N][K]).
// Tile: BM=128, BN=64, BK=32; 4 waves (2x2); per wave 64x32 via 4x2 mfma_16x16x32.
__global__ __launch_bounds__(256) void gemm_bf16x3(
    const __bf16* __restrict__ Ah, const __bf16* __restrict__ Al,
    const __bf16* __restrict__ Bth, const __bf16* __restrict__ Btl,
    float* __restrict__ C, int M, int N, int K)
{
  __shared__ __align__(16) __bf16 sAh[128][40];
  __shared__ __align__(16) __bf16 sAl[128][40];
  __shared__ __align__(16) __bf16 sBh[64][40];
  __shared__ __align__(16) __bf16 sBl[64][40];
  int tid = threadIdx.x;
  int lane = tid & 63, wave = tid >> 6;
  int wr = wave >> 1, wc = wave & 1;
  int rowBase = blockIdx.y << 7, colBase = blockIdx.x << 6;

  int ar = tid >> 2;      // 0..63
  int ac = tid & 3;       // 16B chunk within 64B row

  short8 rAh0, rAh1, rAl0, rAl1, rBh, rBl;
  auto loadA = [&](int k0){
    rAh0 = *(const short8*)(Ah + (size_t)(rowBase + ar     )*K + k0 + ac*8);
    rAh1 = *(const short8*)(Ah + (size_t)(rowBase + ar + 64)*K + k0 + ac*8);
    rAl0 = *(const short8*)(Al + (size_t)(rowBase + ar     )*K + k0 + ac*8);
    rAl1 = *(const short8*)(Al + (size_t)(rowBase + ar + 64)*K + k0 + ac*8);
    rBh  = *(const short8*)(Bth + (size_t)(colBase + ar)*K + k0 + ac*8);
    rBl  = *(const short8*)(Btl + (size_t)(colBase + ar)*K + k0 + ac*8);
  };

  f32x4 acc[4][2];
  #pragma unroll
  for (int m = 0; m < 4; m++)
    #pragma unroll
    for (int n = 0; n < 2; n++) acc[m][n] = (f32x4){0.f,0.f,0.f,0.f};

  loadA(0);
  int nsteps = K >> 5;
  for (int s = 0; s < nsteps; ++s){
    __syncthreads();                 // previous compute done reading LDS
    *(short8*)&sAh[ar][ac*8]      = rAh0;
    *(short8*)&sAh[ar+64][ac*8]   = rAh1;
    *(short8*)&sAl[ar][ac*8]      = rAl0;
    *(short8*)&sAl[ar+64][ac*8]   = rAl1;
    *(short8*)&sBh[ar][ac*8]      = rBh;
    *(short8*)&sBl[ar][ac*8]      = rBl;
    if (s + 1 < nsteps) loadA((s+1) << 5);
    __syncthreads();                 // LDS tile ready

    int kslot = lane >> 4;
    bf16x8 fah[4], fal[4], fbh[2], fbl[2];
    #pragma unroll
    for (int m = 0; m < 4; m++){
      int r = wr*64 + m*16 + (lane & 15);
      fah[m] = *(const bf16x8*)&sAh[r][kslot*8];
      fal[m] = *(const bf16x8*)&sAl[r][kslot*8];
    }
    #pragma unroll
    for (int n = 0; n < 2; n++){
      int c = wc*32 + n*16 + (lane & 15);
      fbh[n] = *(const bf16x8*)&sBh[c][kslot*8];
      fbl[n] = *(const bf16x8*)&sBl[c][kslot*8];
    }
    #pragma unroll
    for (int m = 0; m < 4; m++)
      #pragma unroll
      for (int n = 0; n < 2; n++){
        acc[m][n] = __builtin_amdgcn_mfma_f32_16x16x32_bf16(fah[m], fbh[n], acc[m][n], 0,0,0);
        acc[m][n] = __builtin_amdgcn_mfma_f32_16x16x32_bf16(fah[m], fbl[n], acc[m][n], 0,0,0);
        acc[m][n] = __builtin_amdgcn_mfma_f32_16x16x32_bf16(fal[m], fbh[n], acc[m][n], 0,0,0);
      }
  }

  int rg = lane >> 4, cl = lane & 15;
  #pragma unroll
  for (int m = 0; m < 4; m++)
    #pragma unroll
    for (int n = 0; n < 2; n++)
      #pragma unroll
      for (int j = 0; j < 4; j++)
        C[(size_t)(rowBase + wr*64 + m*16 + rg*4 + j)*N + colBase + wc*32 + n*16 + cl] = acc[m][n][j];
}

// ---------- generic f32 tiled GEMM (small layers) ----------
__global__ __launch_bounds__(256) void gemm_f32(const float* __restrict__ A,
    const float* __restrict__ B, float* __restrict__ C, int M, int N, int K){
  __shared__ float As[16][65];
  __shared__ float Bs[16][65];
  int tid = threadIdx.x;
  int tx = tid & 15, ty = tid >> 4;
  int rowBase = blockIdx.y << 6, colBase = blockIdx.x << 6;
  float acc[4][4] = {{0.f}};
  for (int k0 = 0; k0 < K; k0 += 16){
    #pragma unroll
    for (int i = 0; i < 4; i++){
      int l = tid + i*256; int r = l >> 4, c = l & 15;
      As[c][r] = A[(size_t)(rowBase + r)*K + k0 + c];
    }
    #pragma unroll
    for (int i = 0; i < 4; i++){
      int l = tid + i*256; int r = l >> 6, c = l & 63;
      Bs[r][c] = B[(size_t)(k0 + r)*N + colBase + c];
    }
    __syncthreads();
    #pragma unroll
    for (int kk = 0; kk < 16; kk++){
      float a[4], b[4];
      #pragma unroll
      for (int i = 0; i < 4; i++){ a[i] = As[kk][ty*4+i]; b[i] = Bs[kk][tx*4+i]; }
      #pragma unroll
      for (int i = 0; i < 4; i++)
        #pragma unroll
        for (int j = 0; j < 4; j++) acc[i][j] = fmaf(a[i], b[j], acc[i][j]);
    }
    __syncthreads();
  }
  #pragma unroll
  for (int i = 0; i < 4; i++)
    #pragma unroll
    for (int j = 0; j < 4; j++)
      C[(size_t)(rowBase + ty*4 + i)*N + colBase + tx*4 + j] = acc[i][j];
}

// ---------- GAT attention coefficients ----------
__global__ __launch_bounds__(256) void att_kernel(const float* __restrict__ h,
    const float* __restrict__ att_src, const float* __restrict__ att_dst,
    float* __restrict__ asrc, float* __restrict__ adst, int N){
  __shared__ float4 red[256];
  int i = blockIdx.x, t = threadIdx.x;
  float h0 = h[(size_t)i*512 + t];
  float h1 = h[(size_t)i*512 + 256 + t];
  float4 v = make_float4(h0*att_src[t], h1*att_src[256+t], h0*att_dst[t], h1*att_dst[256+t]);
  red[t] = v; __syncthreads();
  for (int s = 128; s > 0; s >>= 1){
    if (t < s){ red[t].x += red[t+s].x; red[t].y += red[t+s].y;
                red[t].z += red[t+s].z; red[t].w += red[t+s].w; }
    __syncthreads();
  }
  if (t == 0){ asrc[2*i] = red[0].x; asrc[2*i+1] = red[0].y;
               adst[2*i] = red[0].z; adst[2*i+1] = red[0].w; }
}

// ---------- CSR build ----------
__global__ void deg_init(int* deg, int N){
  int i = blockIdx.x*blockDim.x + threadIdx.x;
  if (i < N) deg[i] = 1;   // self-loop
}
__global__ void deg_count(const int* __restrict__ dst, int* deg, int E){
  int e = blockIdx.x*blockDim.x + threadIdx.x;
  if (e < E) atomicAdd(&deg[dst[e]], 1);
}
// single-block exclusive scan (n <= 32768)
__global__ __launch_bounds__(1024) void scan_kernel(const int* __restrict__ deg,
                                                    int* __restrict__ offs, int n){
  __shared__ int part[1024];
  int t = threadIdx.x;
  int chunk = (n + 1023) >> 10;
  int base = t * chunk;
  int loc[32];
  int local = 0;
  for (int k = 0; k < chunk; k++){
    int idx = base + k; loc[k] = local;
    if (idx < n) local += deg[idx];
  }
  part[t] = local; __syncthreads();
  for (int off = 1; off < 1024; off <<= 1){
    int v = (t >= off) ? part[t-off] : 0; __syncthreads();
    part[t] += v; __syncthreads();
  }
  int excl = part[t] - local;
  for (int k = 0; k < chunk; k++){
    int idx = base + k;
    if (idx < n) offs[idx] = excl + loc[k];
  }
  if (t == 1023) offs[n] = part[1023];
}
__global__ void copy_int(const int* __restrict__ a, int* __restrict__ b, int n){
  int i = blockIdx.x*blockDim.x + threadIdx.x;
  if (i < n) b[i] = a[i];
}
__global__ void scatter_edges(const int* __restrict__ src, const int* __restrict__ dst,
                              int* cursor, int* __restrict__ ssrc, int E, int N){
  int e = blockIdx.x*blockDim.x + threadIdx.x;
  if (e < E){
    int d = dst[e]; int pos = atomicAdd(&cursor[d], 1); ssrc[pos] = src[e];
  } else if (e < E + N){
    int i = e - E; int pos = atomicAdd(&cursor[i], 1); ssrc[pos] = i;
  }
}

// ---------- GAT aggregation (one block per destination node) ----------
__global__ __launch_bounds__(256) void gat_aggregate(const float* __restrict__ h,
    const int* __restrict__ offs, const int* __restrict__ ssrc,
    const float* __restrict__ asrc, const float* __restrict__ adst,
    const float* __restrict__ bias, float* __restrict__ out, int N){
  __shared__ float2 red[256];
  __shared__ float alpha_s[256];
  int d = blockIdx.x, t = threadIdx.x;
  int beg = offs[d], end = offs[d+1];
  float ad0 = adst[2*d], ad1 = adst[2*d+1];
  // pass 1: per-head max
  float m0 = -1e30f, m1 = -1e30f;
  for (int o = beg + t; o < end; o += 256){
    int s = ssrc[o];
    m0 = fmaxf(m0, leaky02(asrc[2*s]   + ad0));
    m1 = fmaxf(m1, leaky02(asrc[2*s+1] + ad1));
  }
  red[t] = make_float2(m0, m1); __syncthreads();
  for (int s2 = 128; s2 > 0; s2 >>= 1){
    if (t < s2){ red[t].x = fmaxf(red[t].x, red[t+s2].x);
                 red[t].y = fmaxf(red[t].y, red[t+s2].y); }
    __syncthreads();
  }
  m0 = red[0].x; m1 = red[0].y; __syncthreads();
  // pass 2: denominators
  float s0 = 0.f, s1 = 0.f;
  for (int o = beg + t; o < end; o += 256){
    int s = ssrc[o];
    s0 += expf(leaky02(asrc[2*s]   + ad0) - m0);
    s1 += expf(leaky02(asrc[2*s+1] + ad1) - m1);
  }
  red[t] = make_float2(s0, s1); __syncthreads();
  for (int s2 = 128; s2 > 0; s2 >>= 1){
    if (t < s2){ red[t].x += red[t+s2].x; red[t].y += red[t+s2].y; }
    __syncthreads();
  }
  float inv0 = 1.f / red[0].x, inv1 = 1.f / red[0].y;
  __syncthreads();
  // pass 3: alphas cached in LDS per 128-edge chunk; thread t owns dims (2t,2t+1)
  int dim = 2*t;
  int head = dim >> 8;
  float accx = 0.f, accy = 0.f;
  for (int c0 = beg; c0 < end; c0 += 128){
    int cnt = end - c0; if (cnt > 128) cnt = 128;
    __syncthreads();
    if (t < 2*cnt){
      int eo = t >> 1, hh = t & 1;
      int s = ssrc[c0 + eo];
      float ec = leaky02(asrc[2*s + hh] + (hh ? ad1 : ad0));
      alpha_s[t] = expf(ec - (hh ? m1 : m0)) * (hh ? inv1 : inv0);
    }
    __syncthreads();
    for (int o = 0; o < cnt; ++o){
      int s = ssrc[c0 + o];
      float al = alpha_s[2*o + head];
      float2 v = *(const float2*)&h[(size_t)s*512 + dim];
      accx = fmaf(al, v.x, accx);
      accy = fmaf(al, v.y, accy);
    }
  }
  out[(size_t)d*512 + dim]     = fmaxf(accx + bias[dim],   0.f);   // conv bias + relu
  out[(size_t)d*512 + dim + 1] = fmaxf(accy + bias[dim+1], 0.f);
}

// ---------- bias + LayerNorm + ReLU (in place), C <= 256 ----------
__global__ __launch_bounds__(256) void ln_relu(float* __restrict__ Z,
    const float* __restrict__ bias, const float* __restrict__ g,
    const float* __restrict__ bg, int R, int C){
  __shared__ float red[256];
  int r = blockIdx.x, t = threadIdx.x;
  bool act = t < C;
  float z = 0.f;
  if (act) z = Z[(size_t)r*C + t] + bias[t];
  red[t] = z; __syncthreads();
  for (int s = 128; s > 0; s >>= 1){ if (t < s) red[t] += red[t+s]; __syncthreads(); }
  float mean = red[0] / C; __syncthreads();
  float dz = act ? z - mean : 0.f;
  red[t] = dz*dz; __syncthreads();
  for (int s = 128; s > 0; s >>= 1){ if (t < s) red[t] += red[t+s]; __syncthreads(); }
  float var = red[0] / C;
  float rs = 1.f / sqrtf(var + 1e-5f);
  if (act) Z[(size_t)r*C + t] = fmaxf(dz*rs*g[t] + bg[t], 0.f);
}

// ---------- final 64->3 GEMM, packs (x,y,z,|h|^2) ----------
__global__ __launch_bounds__(256) void final_hf4(const float* __restrict__ A,
    const float* __restrict__ W3s, const float* __restrict__ b3,
    float4* __restrict__ hf4, int N){
  __shared__ float w[64*3];
  __shared__ float b[3];
  if (threadIdx.x < 192) w[threadIdx.x] = W3s[threadIdx.x];
  if (threadIdx.x < 3)   b[threadIdx.x] = b3[threadIdx.x];
  __syncthreads();
  int r = blockIdx.x*blockDim.x + threadIdx.x;
  if (r >= N) return;
  float x = b[0], y = b[1], z = b[2];
  #pragma unroll 8
  for (int k = 0; k < 64; ++k){
    float a = A[(size_t)r*64 + k];
    x = fmaf(a, w[k*3],   x);
    y = fmaf(a, w[k*3+1], y);
    z = fmaf(a, w[k*3+2], z);
  }
  float sq = x*x + y*y + z*z;
  hf4[r] = make_float4(x, y, z, sq);
}

// ---------- cdist ----------
__global__ __launch_bounds__(256) void cdist_kernel(const float4* __restrict__ hf,
                                                    float* __restrict__ out, int N){
  int i = blockIdx.y;
  int j0 = (blockIdx.x*256 + threadIdx.x)*4;
  float4 a = hf[i];
  float4 r;
  float4 b0 = hf[j0], b1 = hf[j0+1], b2 = hf[j0+2], b3 = hf[j0+3];
  float d;
  d = a.w + b0.w - 2.f*(a.x*b0.x + a.y*b0.y + a.z*b0.z); r.x = sqrtf(fmaxf(d, 0.f));
  d = a.w + b1.w - 2.f*(a.x*b1.x + a.y*b1.y + a.z*b1.z); r.y = sqrtf(fmaxf(d, 0.f));
  d = a.w + b2.w - 2.f*(a.x*b2.x + a.y*b2.y + a.z*b2.z); r.z = sqrtf(fmaxf(d, 0.f));
  d = a.w + b3.w - 2.f*(a.x*b3.x + a.y*b3.y + a.z*b3.z); r.w = sqrtf(fmaxf(d, 0.f));
  *(float4*)&out[(size_t)i*N + j0] = r;
}

// ---------------------------------------------------------------------------
extern "C" void kernel_launch(void* const* d_in, const int* in_sizes, int n_in,
                              void* d_out, int out_size, void* d_ws, size_t ws_size,
                              hipStream_t stream){
  const int N = in_sizes[0] / 512;        // 16384
  const int E = in_sizes[1] / 2;          // 524288

  const float* x         = (const float*)d_in[0];
  const int*   ei        = (const int*)  d_in[1];
  const float* W         = (const float*)d_in[2];
  const float* att_src   = (const float*)d_in[3];
  const float* att_dst   = (const float*)d_in[4];
  const float* bias_conv = (const float*)d_in[5];
  const float* Wa  = (const float*)d_in[6];
  const float* ba  = (const float*)d_in[7];
  const float* ga  = (const float*)d_in[8];
  const float* bga = (const float*)d_in[9];
  const float* W1  = (const float*)d_in[10];
  const float* b1  = (const float*)d_in[11];
  const float* g1  = (const float*)d_in[12];
  const float* bg1 = (const float*)d_in[13];
  const float* W2  = (const float*)d_in[14];
  const float* b2  = (const float*)d_in[15];
  const float* g2  = (const float*)d_in[16];
  const float* bg2 = (const float*)d_in[17];
  const float* W3  = (const float*)d_in[18];
  const float* b3  = (const float*)d_in[19];

  const int* e_src = ei;
  const int* e_dst = ei + E;

  size_t off = 0;
  auto alloc = [&](size_t bytes)->char*{
    size_t o = off; off += (bytes + 255) & ~(size_t)255;
    return (char*)d_ws + o;
  };
  float* bufA  = (float*)alloc((size_t)N*512*4);
  float* bufB  = (float*)alloc((size_t)N*512*4);
  __bf16* Ah   = (__bf16*)alloc((size_t)N*512*2);
  __bf16* Al   = (__bf16*)alloc((size_t)N*512*2);
  __bf16* Bth  = (__bf16*)alloc(512*512*2);
  __bf16* Btl  = (__bf16*)alloc(512*512*2);
  float* Wsc   = (float*)alloc(512*512*4);
  float* Wasc  = (float*)alloc(512*256*4);
  float* W1sc  = (float*)alloc(256*128*4);
  float* W2sc  = (float*)alloc(128*64*4);
  float* W3sc  = (float*)alloc(64*3*4);
  float* ss    = (float*)alloc(512*4);
  float* asrc  = (float*)alloc((size_t)N*2*4);
  float* adst  = (float*)alloc((size_t)N*2*4);
  float4* hf4  = (float4*)alloc((size_t)N*16);
  int* deg     = (int*)alloc((size_t)N*4);
  int* offs    = (int*)alloc((size_t)(N+1)*4);
  int* cursor  = (int*)alloc((size_t)N*4);
  int* ssrc    = (int*)alloc((size_t)(E+N)*4);

  float* outF = (float*)d_out;

  // ---- stage 1: l2norm(x) folded into W ; h = x @ W' via split-bf16 MFMA ----
  hipMemsetAsync(ss, 0, 512*4, stream);
  colnorm_sq<<<dim3(2,128), 256, 0, stream>>>(x, ss, N, 512);
  scale_rows<<<(512*512+255)/256, 256, 0, stream>>>(W, ss, Wsc, 512, 512);
  split_hl<<<(N*512/4+255)/256, 256, 0, stream>>>(x, Ah, Al, N*512/4);
  split_tr<<<dim3(512/32, 512/32), 256, 0, stream>>>(Wsc, Bth, Btl, 512, 512);
  gemm_bf16x3<<<dim3(512/64, N/128), 256, 0, stream>>>(Ah, Al, Bth, Btl, bufA, N, 512, 512);

  // ---- GAT ----
  att_kernel<<<N, 256, 0, stream>>>(bufA, att_src, att_dst, asrc, adst, N);
  deg_init<<<(N+255)/256, 256, 0, stream>>>(deg, N);
  deg_count<<<(E+255)/256, 256, 0, stream>>>(e_dst, deg, E);
  scan_kernel<<<1, 1024, 0, stream>>>(deg, offs, N);
  copy_int<<<(N+255)/256, 256, 0, stream>>>(offs, cursor, N);
  scatter_edges<<<(E+N+255)/256, 256, 0, stream>>>(e_src, e_dst, cursor, ssrc, E, N);
  gat_aggregate<<<N, 256, 0, stream>>>(bufA, offs, ssrc, asrc, adst, bias_conv, bufB, N);

  // ---- stage 2: l2norm fold -> LN(relu'd_gatout @ Wa' + ba) ----
  hipMemsetAsync(ss, 0, 512*4, stream);
  colnorm_sq<<<dim3(2,128), 256, 0, stream>>>(bufB, ss, N, 512);
  scale_rows<<<(512*256+255)/256, 256, 0, stream>>>(Wa, ss, Wasc, 512, 256);
  split_hl<<<(N*512/4+255)/256, 256, 0, stream>>>(bufB, Ah, Al, N*512/4);
  split_tr<<<dim3(256/32, 512/32), 256, 0, stream>>>(Wasc, Bth, Btl, 512, 256);
  gemm_bf16x3<<<dim3(256/64, N/128), 256, 0, stream>>>(Ah, Al, Bth, Btl, bufA, N, 256, 512);
  ln_relu<<<N, 256, 0, stream>>>(bufA, ba, ga, bga, N, 256);

  // ---- stage 3 ----
  hipMemsetAsync(ss, 0, 512*4, stream);
  colnorm_sq<<<dim3(1,128), 256, 0, stream>>>(bufA, ss, N, 256);
  scale_rows<<<(256*128+255)/256, 256, 0, stream>>>(W1, ss, W1sc, 256, 128);
  gemm_f32<<<dim3(128/64, N/64), 256, 0, stream>>>(bufA, W1sc, bufB, N, 128, 256);
  ln_relu<<<N, 256, 0, stream>>>(bufB, b1, g1, bg1, N, 128);

  // ---- stage 4 ----
  hipMemsetAsync(ss, 0, 512*4, stream);
  colnorm_sq<<<dim3(1,128), 256, 0, stream>>>(bufB, ss, N, 128);
  scale_rows<<<(128*64+255)/256, 256, 0, stream>>>(W2, ss, W2sc, 128, 64);
  gemm_f32<<<dim3(64/64, N/64), 256, 0, stream>>>(bufB, W2sc, bufA, N, 64, 128);
  ln_relu<<<N, 256, 0, stream>>>(bufA, b2, g2, bg2, N, 64);

  // ---- stage 5: final projection + cdist ----
  hipMemsetAsync(ss, 0, 512*4, stream);
  colnorm_sq<<<dim3(1,128), 256, 0, stream>>>(bufA, ss, N, 64);
  scale_rows<<<(64*3+255)/256, 256, 0, stream>>>(W3, ss, W3sc, 64, 3);
  final_hf4<<<(N+255)/256, 256, 0, stream>>>(bufA, W3sc, b3, hf4, N);
  cdist_kernel<<<dim3(N/1024, N), 256, 0, stream>>>(hf4, outF, N);
}